// Round 4
// baseline (354.920 us; speedup 1.0000x reference)
//
#include <hip/hip_runtime.h>

typedef __attribute__((ext_vector_type(8))) short bf16x8;
typedef __attribute__((ext_vector_type(4))) float f32x4;

#define MFMA16(a, b, c) __builtin_amdgcn_mfma_f32_16x16x32_bf16((a), (b), (c), 0, 0, 0)

static __device__ __forceinline__ unsigned short f2bf(float x) {
    union { float f; unsigned u; } v; v.f = x;
    unsigned r = v.u + 0x7fffu + ((v.u >> 16) & 1u);
    return (unsigned short)(r >> 16);
}

// async global->LDS, 16B per lane. LDS dest = wave base + lane*16 (linear).
static __device__ __forceinline__ void gload16(const void* g, void* l) {
    __builtin_amdgcn_global_load_lds(
        (const __attribute__((address_space(1))) unsigned int*)g,
        (__attribute__((address_space(3))) unsigned int*)l, 16, 0, 0);
}

// ---------------- workspace layout (bytes) ----------------
#define WS_POOLED   0u          //  8,388,608  bf16 [4096][1024]
#define WS_LW1T     8388608u    //    262,144  bf16 [512][256]
#define WS_LW2T     8650752u    //  1,048,576  bf16 [1024][512]
#define WS_FWT      9699328u    //  1,048,576  bf16 [512][1024]
#define WS_SCAN     10747904u   //     16,640  int [4097]
#define WS_HEADER   10764544u   //        256  int: {M_c, M_cp}
#define WS_RMB      10764800u   //    409,600  int [102400]
#define WS_RMNEXT   11174400u   //    409,600  int [102400]
#define WS_HC       11584000u   // 26,214,400  bf16 [102400][128]
#define WS_SCRATCH  37798400u   // 33,554,432  f32 [4096][2][1024]
#define WS_HID      71352832u   // up to 104,857,600  bf16 [102400][512]

// ---------------- scan: exclusive prefix sum of nfpc[4096] ----------------
__global__ void scan_kernel(const int* __restrict__ nfpc, int* __restrict__ scanv,
                            int* __restrict__ header)
{
    __shared__ int s[256];
    const int t = threadIdx.x;
    int loc[16]; int sum = 0;
    #pragma unroll
    for (int i = 0; i < 16; ++i) { loc[i] = sum; sum += nfpc[t * 16 + i]; }
    s[t] = sum;
    __syncthreads();
    for (int d = 1; d < 256; d <<= 1) {
        int v = (t >= d) ? s[t - d] : 0;
        __syncthreads();
        s[t] += v;
        __syncthreads();
    }
    int excl = (t == 0) ? 0 : s[t - 1];
    #pragma unroll
    for (int i = 0; i < 16; ++i) scanv[t * 16 + i] = excl + loc[i];
    if (t == 255) {
        int M = s[255];
        scanv[4096] = M;
        header[0] = M;
        header[1] = (M + 127) & ~127;
    }
}

// ---------------- rowmap: per compact row -> batch, cyclic-next row ----------------
__global__ void rowmap_kernel(const int* __restrict__ scanv, const int* __restrict__ header,
                              int* __restrict__ rm_b, int* __restrict__ rm_next)
{
    int r = blockIdx.x * 256 + threadIdx.x;     // grid covers 102400
    if (r >= 102400) return;
    const int Mc = header[0];
    if (r >= Mc) { rm_b[r] = -1; rm_next[r] = r; return; }
    int lo = 0, hi = 4096;
    while (hi - lo > 1) { int mid = (lo + hi) >> 1; if (scanv[mid] <= r) lo = mid; else hi = mid; }
    int b = lo, ii = r - scanv[b], n = scanv[b + 1] - scanv[b];
    rm_b[r] = b;
    rm_next[r] = (ii + 1 == n) ? scanv[b] : r + 1;
}

// ---------------- zero the h_c padding rows [M_c, M_cp) ----------------
__global__ void zeropad_kernel(const int* __restrict__ header, unsigned short* __restrict__ h_c)
{
    const int Mc = header[0], Mcp = header[1];
    const int nel = (Mcp - Mc) * 128;
    for (int e = blockIdx.x * 256 + threadIdx.x; e < nel; e += gridDim.x * 256)
        h_c[Mc * 128 + e] = 0;
}

// ---------------- weight prep: fp32 -> bf16, transposed to [N][K] ----------------
__global__ void convert_kernel(
    const float* __restrict__ lw1, const float* __restrict__ lw2, const float* __restrict__ fw,
    short* __restrict__ lw1t, short* __restrict__ lw2t, short* __restrict__ fwt)
{
    int t = blockIdx.x * 256 + threadIdx.x;
    if (t < 131072) {                       // lw1t[512][256] <- lw1[256][512]
        int n = t >> 8, k = t & 255;
        lw1t[t] = (short)f2bf(lw1[k * 512 + n]);
    } else if (t < 131072 + 524288) {       // lw2t[1024][512] <- lw2[512][1024]
        int u = t - 131072;
        int n = u >> 9, k = u & 511;
        lw2t[u] = (short)f2bf(lw2[k * 1024 + n]);
    } else if (t < 131072 + 524288 + 524288) { // fwt[512][1024] <- fw[1024][511], row 511 = 0
        int v = t - 655360;
        int n = v >> 10, k = v & 1023;
        fwt[v] = (n < 511) ? (short)f2bf(fw[k * 511 + n]) : (short)0;
    }
}

// ---------------- corner MLP -> compacted h_c bf16 [M_c][128] ----------------
#define CB 4
__global__ __launch_bounds__(256, 2) void corner_kernel(
    const float* __restrict__ fpoc,
    const float* __restrict__ cw1, const float* __restrict__ cb1,
    const float* __restrict__ cw2, const float* __restrict__ cb2,
    const int* __restrict__ scanv,
    unsigned short* __restrict__ h_c)
{
    __shared__ float s_h1[CB * 25 * 64];
    __shared__ float s_cw2[64 * 128];
    __shared__ float s_x[CB * 25 * 2];
    __shared__ int s_off[CB], s_nn[CB];
    const int b0 = blockIdx.x * CB;
    const int t = threadIdx.x;

    for (int e = t; e < 64 * 128; e += 256) s_cw2[e] = cw2[e];
    for (int e = t; e < CB * 50; e += 256) s_x[e] = fpoc[b0 * 50 + e];
    if (t < CB) { int o = scanv[b0 + t]; s_off[t] = o; s_nn[t] = scanv[b0 + t + 1] - o; }
    __syncthreads();

    for (int e = t; e < CB * 25 * 64; e += 256) {
        int i = e >> 6, j = e & 63;
        float v = s_x[i * 2] * cw1[j] + s_x[i * 2 + 1] * cw1[64 + j] + cb1[j];
        s_h1[e] = fmaxf(v, 0.f);
    }
    __syncthreads();

    for (int e = t; e < CB * 25 * 128; e += 256) {
        int i = e >> 7, j = e & 127;
        int g = i / 25, ii = i % 25;
        if (ii < s_nn[g]) {
            float a = cb2[j];
            const float* h1r = &s_h1[i * 64];
            #pragma unroll
            for (int k = 0; k < 64; ++k) a += h1r[k] * s_cw2[k * 128 + j];
            h_c[(size_t)(s_off[g] + ii) * 128 + j] = f2bf(a);
        }
    }
}

// ---------------- gemm1: pair(gathered from h_c) @ lw1t^T -> relu+lb1 -> hid ----------
__global__ __launch_bounds__(256, 2) void gemm1_kernel(
    const unsigned short* __restrict__ h_c,   // [M_cp][128]
    const short* __restrict__ lw1t,           // [512][256]
    const float* __restrict__ lb1,
    const int* __restrict__ rm_next,
    const int* __restrict__ header,
    unsigned short* __restrict__ hid,         // [crows][512] chunk-local
    int row0, int pm)
{
    __shared__ __align__(16) char ldsA[16384];
    __shared__ __align__(16) char ldsB[16384];
    __shared__ int s_next[128];

    const int Mcp = header[1];
    const int nwg = pm * 4;
    int bid = blockIdx.x;
    int bid2 = (bid & 7) * (nwg >> 3) + (bid >> 3);   // XCD swizzle (nwg%8==0)
    const int pr = bid2 >> 2, pc = bid2 & 3;
    const int Rl = pr * 128;                          // chunk-local
    const int R = row0 + Rl;                          // global compact row base
    if (R >= Mcp) return;

    const int t = threadIdx.x;
    const int w = t >> 6, l = t & 63, q = l >> 4, ln = l & 15;
    const int wr = w >> 1, wc = w & 1;

    if (t < 128) s_next[t] = rm_next[R + t];
    __syncthreads();

    f32x4 acc[4][4];
    #pragma unroll
    for (int m = 0; m < 4; ++m)
        #pragma unroll
        for (int n = 0; n < 4; ++n) acc[m][n] = 0;

    #pragma unroll
    for (int kt = 0; kt < 4; ++kt) {
        const int k0 = kt * 64;
        // ---- stage A: gather pair rows (pre-swizzled source)
        #pragma unroll
        for (int i = 0; i < 4; ++i) {
            int o = i * 4096 + t * 16;
            int row = o >> 7, colb = o & 127;
            int colb2 = colb ^ ((row & 7) << 4);
            int k = k0 + (colb2 >> 1);                // 0..255 (compile-time half per kt)
            int srow, kk2;
            if (k < 128) { srow = R + row; kk2 = k; }
            else { srow = s_next[row]; kk2 = k - 128; }
            const unsigned short* src = h_c + (size_t)srow * 128 + kk2;
            gload16(src, ldsA + o);
        }
        // ---- stage B from lw1t
        #pragma unroll
        for (int i = 0; i < 4; ++i) {
            int o = i * 4096 + t * 16;
            int row = o >> 7, colb = o & 127;
            int colb2 = colb ^ ((row & 7) << 4);
            const short* src = lw1t + (pc * 128 + row) * 256 + k0 + (colb2 >> 1);
            gload16(src, ldsB + o);
        }
        asm volatile("s_waitcnt vmcnt(0)");
        __syncthreads();
        #pragma unroll
        for (int kk = 0; kk < 2; ++kk) {
            bf16x8 af[4], bf[4];
            #pragma unroll
            for (int m = 0; m < 4; ++m) {
                int row = wr * 64 + m * 16 + ln;
                int off = (row * 128 + kk * 64 + q * 16) ^ ((row & 7) << 4);
                af[m] = *(const bf16x8*)(ldsA + off);
            }
            #pragma unroll
            for (int n = 0; n < 4; ++n) {
                int row = wc * 64 + n * 16 + ln;
                int off = (row * 128 + kk * 64 + q * 16) ^ ((row & 7) << 4);
                bf[n] = *(const bf16x8*)(ldsB + off);
            }
            #pragma unroll
            for (int m = 0; m < 4; ++m)
                #pragma unroll
                for (int n = 0; n < 4; ++n)
                    acc[m][n] = MFMA16(af[m], bf[n], acc[m][n]);
        }
        __syncthreads();
    }
    // ---- epilogue: relu + bias -> hid bf16 (chunk-local rows)
    #pragma unroll
    for (int n = 0; n < 4; ++n) {
        int col = pc * 128 + wc * 64 + n * 16 + ln;
        float bias = lb1[col];
        #pragma unroll
        for (int m = 0; m < 4; ++m) {
            int lrow = Rl + wr * 64 + m * 16 + q * 4;
            #pragma unroll
            for (int r = 0; r < 4; ++r)
                hid[(size_t)(lrow + r) * 512 + col] = f2bf(fmaxf(acc[m][n][r] + bias, 0.f));
        }
    }
}

// ---------------- gemm2: hid @ lw2t^T + segmented maxpool -> scratch partials ----------
__global__ __launch_bounds__(256, 2) void gemm2_kernel(
    const unsigned short* __restrict__ hid,   // [crows][512] chunk-local
    const short* __restrict__ lw2t,           // [1024][512]
    const int* __restrict__ rm_b,
    const int* __restrict__ scanv,
    const int* __restrict__ header,
    float* __restrict__ scratch,              // [4096][2][1024] f32
    int row0, int pm)
{
    __shared__ __align__(16) char smem[33280];   // K-loop: A(16K)+B(16K); epilogue: f32[64][130]
    __shared__ int s_batch[128];

    const int Mcp = header[1];
    const int nwg = pm * 8;
    int bid = blockIdx.x;
    int bid2 = (bid & 7) * (nwg >> 3) + (bid >> 3);
    const int pr = bid2 >> 3, pc = bid2 & 7;
    const int Rl = pr * 128;
    const int R = row0 + Rl;
    if (R >= Mcp) return;

    const int t = threadIdx.x;
    const int w = t >> 6, l = t & 63, q = l >> 4, ln = l & 15;
    const int wr = w >> 1, wc = w & 1;
    char* ldsA = smem;
    char* ldsB = smem + 16384;

    if (t < 128) s_batch[t] = rm_b[R + t];
    __syncthreads();

    f32x4 acc[4][4];
    #pragma unroll
    for (int m = 0; m < 4; ++m)
        #pragma unroll
        for (int n = 0; n < 4; ++n) acc[m][n] = 0;

    for (int kt = 0; kt < 8; ++kt) {
        const int k0 = kt * 64;
        #pragma unroll
        for (int i = 0; i < 4; ++i) {
            int o = i * 4096 + t * 16;
            int row = o >> 7, colb = o & 127;
            int colb2 = colb ^ ((row & 7) << 4);
            const unsigned short* src = hid + (size_t)(Rl + row) * 512 + k0 + (colb2 >> 1);
            gload16(src, ldsA + o);
        }
        #pragma unroll
        for (int i = 0; i < 4; ++i) {
            int o = i * 4096 + t * 16;
            int row = o >> 7, colb = o & 127;
            int colb2 = colb ^ ((row & 7) << 4);
            const short* src = lw2t + (pc * 128 + row) * 512 + k0 + (colb2 >> 1);
            gload16(src, ldsB + o);
        }
        asm volatile("s_waitcnt vmcnt(0)");
        __syncthreads();
        #pragma unroll
        for (int kk = 0; kk < 2; ++kk) {
            bf16x8 af[4], bf[4];
            #pragma unroll
            for (int m = 0; m < 4; ++m) {
                int row = wr * 64 + m * 16 + ln;
                int off = (row * 128 + kk * 64 + q * 16) ^ ((row & 7) << 4);
                af[m] = *(const bf16x8*)(ldsA + off);
            }
            #pragma unroll
            for (int n = 0; n < 4; ++n) {
                int row = wc * 64 + n * 16 + ln;
                int off = (row * 128 + kk * 64 + q * 16) ^ ((row & 7) << 4);
                bf[n] = *(const bf16x8*)(ldsB + off);
            }
            #pragma unroll
            for (int m = 0; m < 4; ++m)
                #pragma unroll
                for (int n = 0; n < 4; ++n)
                    acc[m][n] = MFMA16(af[m], bf[n], acc[m][n]);
        }
        __syncthreads();
    }

    // ---- segmented maxpool epilogue: stage 64-row halves to LDS, walk columns
    float* s_f32 = (float*)smem;    // [64][130] f32 (stride 130 -> 2-way conflicts only)
    float curmax = 0.f;
    int curb = -1;
    #pragma unroll 1
    for (int h = 0; h < 2; ++h) {
        if (wr == h) {
            #pragma unroll
            for (int m = 0; m < 4; ++m)
                #pragma unroll
                for (int n = 0; n < 4; ++n)
                    #pragma unroll
                    for (int r = 0; r < 4; ++r)
                        s_f32[(m * 16 + q * 4 + r) * 130 + wc * 64 + n * 16 + ln] = acc[m][n][r];
        }
        __syncthreads();
        if (t < 128) {
            for (int row = 0; row < 64; ++row) {
                int b = s_batch[h * 64 + row];
                float v = s_f32[row * 130 + t];
                if (b == curb) {
                    curmax = fmaxf(curmax, v);
                } else {
                    if (curb >= 0) {
                        int slot = (scanv[curb] < R) ? 1 : 0;
                        scratch[((size_t)curb * 2 + slot) * 1024 + pc * 128 + t] = curmax;
                    }
                    curb = b;
                    curmax = v;
                }
            }
        }
        __syncthreads();
    }
    if (t < 128 && curb >= 0) {
        int slot = (scanv[curb] < R) ? 1 : 0;
        scratch[((size_t)curb * 2 + slot) * 1024 + pc * 128 + t] = curmax;
    }
}

// ---------------- merge: max of <=2 partials + lb2 -> pooled bf16 ----------------
__global__ void merge_kernel(const float* __restrict__ scratch, const int* __restrict__ scanv,
                             const float* __restrict__ lb2, unsigned short* __restrict__ pooled_b)
{
    const int bid = blockIdx.x;          // 16384 blocks
    const int b = bid >> 2;
    const int col = (bid & 3) * 256 + threadIdx.x;
    const int o0 = scanv[b], o1 = scanv[b + 1];
    const bool spans = (o0 >> 7) != ((o1 - 1) >> 7);
    float v = scratch[((size_t)b * 2) * 1024 + col];
    if (spans) v = fmaxf(v, scratch[((size_t)b * 2 + 1) * 1024 + col]);
    pooled_b[(size_t)b * 1024 + col] = f2bf(v + lb2[col]);
}

// ---------------- final: pooled[4096,1024] @ fw[1024,511] + fb ----------------
__global__ __launch_bounds__(512, 2) void final_kernel(
    const unsigned short* __restrict__ pooled_b,
    const short* __restrict__ fwt,    // bf16 [512][1024]
    const float* __restrict__ fb,
    float* __restrict__ out)
{
    const int tid = threadIdx.x;
    const int w = tid >> 6, l = tid & 63, q = l >> 4, ln = l & 15;
    const int rb = blockIdx.x * 128 + w * 16;
    const int nb0 = blockIdx.y * 64;

    f32x4 acc[4];
    #pragma unroll
    for (int j = 0; j < 4; ++j) acc[j] = 0;

    const short* pb = (const short*)pooled_b;
    #pragma unroll 4
    for (int ks = 0; ks < 32; ++ks) {
        bf16x8 a = *(const bf16x8*)(pb + (rb + ln) * 1024 + ks * 32 + q * 8);
        #pragma unroll
        for (int j = 0; j < 4; ++j) {
            bf16x8 bf = *(const bf16x8*)(fwt + (nb0 + j * 16 + ln) * 1024 + ks * 32 + q * 8);
            acc[j] = MFMA16(a, bf, acc[j]);
        }
    }
    #pragma unroll
    for (int j = 0; j < 4; ++j) {
        int col = nb0 + j * 16 + ln;
        if (col < 511) {
            float bias = fb[col];
            #pragma unroll
            for (int r = 0; r < 4; ++r) {
                int row = rb + q * 4 + r;
                out[row * 511 + col] = acc[j][r] + bias;
            }
        }
    }
}

extern "C" void kernel_launch(void* const* d_in, const int* in_sizes, int n_in,
                              void* d_out, int out_size, void* d_ws, size_t ws_size,
                              hipStream_t stream)
{
    const float* fpoc = (const float*)d_in[0];
    const float* cw1  = (const float*)d_in[1];
    const float* cb1  = (const float*)d_in[2];
    const float* cw2  = (const float*)d_in[3];
    const float* cb2  = (const float*)d_in[4];
    const float* lw1  = (const float*)d_in[5];
    const float* lb1  = (const float*)d_in[6];
    const float* lw2  = (const float*)d_in[7];
    const float* lb2  = (const float*)d_in[8];
    const float* fw   = (const float*)d_in[9];
    const float* fb   = (const float*)d_in[10];
    const int*  nfpc  = (const int*)d_in[11];

    char* ws = (char*)d_ws;
    unsigned short* pooled_b = (unsigned short*)(ws + WS_POOLED);
    short* lw1t   = (short*)(ws + WS_LW1T);
    short* lw2t   = (short*)(ws + WS_LW2T);
    short* fwt    = (short*)(ws + WS_FWT);
    int*   scanv  = (int*)(ws + WS_SCAN);
    int*   header = (int*)(ws + WS_HEADER);
    int*   rm_b   = (int*)(ws + WS_RMB);
    int*   rm_next= (int*)(ws + WS_RMNEXT);
    unsigned short* h_c = (unsigned short*)(ws + WS_HC);
    float* scratch = (float*)(ws + WS_SCRATCH);
    unsigned short* hid = (unsigned short*)(ws + WS_HID);

    // adaptive chunking of hid (worst case 102400 rows x 512 x bf16 = 100 MB)
    size_t avail = (ws_size > WS_HID) ? ws_size - WS_HID : 0;
    int n_chunks = 1;
    while (n_chunks < 16 && (size_t)(104857600u / n_chunks) > avail) n_chunks <<= 1;
    const int crows = 102400 / n_chunks;
    const int pm = crows / 128;

    hipLaunchKernelGGL(scan_kernel, dim3(1), dim3(256), 0, stream, nfpc, scanv, header);
    hipLaunchKernelGGL(rowmap_kernel, dim3(400), dim3(256), 0, stream, scanv, header, rm_b, rm_next);
    hipLaunchKernelGGL(zeropad_kernel, dim3(64), dim3(256), 0, stream, header, h_c);
    hipLaunchKernelGGL(convert_kernel, dim3(4608), dim3(256), 0, stream,
                       lw1, lw2, fw, lw1t, lw2t, fwt);
    hipLaunchKernelGGL(corner_kernel, dim3(1024), dim3(256), 0, stream,
                       fpoc, cw1, cb1, cw2, cb2, scanv, h_c);
    for (int c = 0; c < n_chunks; ++c) {
        int row0 = c * crows;
        hipLaunchKernelGGL(gemm1_kernel, dim3(pm * 4), dim3(256), 0, stream,
                           h_c, lw1t, lb1, rm_next, header, hid, row0, pm);
        hipLaunchKernelGGL(gemm2_kernel, dim3(pm * 8), dim3(256), 0, stream,
                           hid, lw2t, rm_b, scanv, header, scratch, row0, pm);
    }
    hipLaunchKernelGGL(merge_kernel, dim3(16384), dim3(256), 0, stream,
                       scratch, scanv, lb2, pooled_b);
    hipLaunchKernelGGL(final_kernel, dim3(32, 8), dim3(512), 0, stream,
                       pooled_b, fwt, fb, (float*)d_out);
}

// Round 5
// 269.717 us; speedup vs baseline: 1.3159x; 1.3159x over previous
//
#include <hip/hip_runtime.h>

typedef __attribute__((ext_vector_type(8))) short bf16x8;
typedef __attribute__((ext_vector_type(4))) float f32x4;

#define MFMA16(a, b, c) __builtin_amdgcn_mfma_f32_16x16x32_bf16((a), (b), (c), 0, 0, 0)

static __device__ __forceinline__ unsigned short f2bf(float x) {
    union { float f; unsigned u; } v; v.f = x;
    unsigned r = v.u + 0x7fffu + ((v.u >> 16) & 1u);
    return (unsigned short)(r >> 16);
}

// async global->LDS, 16B per lane. LDS dest = wave base + lane*16 (linear).
static __device__ __forceinline__ void gload16(const void* g, void* l) {
    __builtin_amdgcn_global_load_lds(
        (const __attribute__((address_space(1))) unsigned int*)g,
        (__attribute__((address_space(3))) unsigned int*)l, 16, 0, 0);
}

// Balanced data-dependent tile assignment: XCD k = bid&7 gets active-tile range
// [T*k/8, T*(k+1)/8) (bijective chunked, m204). pc-fast => contiguous pr per XCD.
// Returns false if this block has no tile.
static __device__ __forceinline__ bool tile_assign(int bid, int apm, int npc_log2,
                                                   int& pr, int& pc) {
    const int k = bid & 7, j = bid >> 3;
    const int T = apm << npc_log2;
    const int lo = (T * k) >> 3, hi = (T * (k + 1)) >> 3;
    const int tix = lo + j;
    if (tix >= hi) return false;
    pc = tix & ((1 << npc_log2) - 1);
    pr = tix >> npc_log2;
    return true;
}

// ---------------- workspace layout (bytes) ----------------
#define WS_POOLED   0u          //  8,388,608  bf16 [4096][1024]
#define WS_LW1T     8388608u    //    262,144  bf16 [512][256]
#define WS_LW2T     8650752u    //  1,048,576  bf16 [1024][512]
#define WS_FWT      9699328u    //  1,048,576  bf16 [512][1024]
#define WS_SCAN     10747904u   //     16,640  int [4097]
#define WS_HEADER   10764544u   //        256  int: {M_c, M_cp}
#define WS_RMB      10764800u   //    409,600  int [102400]
#define WS_RMNEXT   11174400u   //    409,600  int [102400]
#define WS_HC       11584000u   // 26,214,400  bf16 [102400][128]
#define WS_SCRATCH  37798400u   // 33,554,432  f32 [4096][2][1024]
#define WS_HID      71352832u   // up to 104,857,600  bf16 [102400][512]

// ---------------- scan: exclusive prefix sum of nfpc[4096] ----------------
__global__ void scan_kernel(const int* __restrict__ nfpc, int* __restrict__ scanv,
                            int* __restrict__ header)
{
    __shared__ int s[256];
    const int t = threadIdx.x;
    int loc[16]; int sum = 0;
    #pragma unroll
    for (int i = 0; i < 16; ++i) { loc[i] = sum; sum += nfpc[t * 16 + i]; }
    s[t] = sum;
    __syncthreads();
    for (int d = 1; d < 256; d <<= 1) {
        int v = (t >= d) ? s[t - d] : 0;
        __syncthreads();
        s[t] += v;
        __syncthreads();
    }
    int excl = (t == 0) ? 0 : s[t - 1];
    #pragma unroll
    for (int i = 0; i < 16; ++i) scanv[t * 16 + i] = excl + loc[i];
    if (t == 255) {
        int M = s[255];
        scanv[4096] = M;
        header[0] = M;
        header[1] = (M + 127) & ~127;
    }
}

// ---------------- rowmap: per compact row -> batch, cyclic-next row ----------------
__global__ void rowmap_kernel(const int* __restrict__ scanv, const int* __restrict__ header,
                              int* __restrict__ rm_b, int* __restrict__ rm_next)
{
    int r = blockIdx.x * 256 + threadIdx.x;     // grid covers 102400
    if (r >= 102400) return;
    const int Mc = header[0];
    if (r >= Mc) { rm_b[r] = -1; rm_next[r] = r; return; }
    int lo = 0, hi = 4096;
    while (hi - lo > 1) { int mid = (lo + hi) >> 1; if (scanv[mid] <= r) lo = mid; else hi = mid; }
    int b = lo, ii = r - scanv[b], n = scanv[b + 1] - scanv[b];
    rm_b[r] = b;
    rm_next[r] = (ii + 1 == n) ? scanv[b] : r + 1;
}

// ---------------- zero the h_c padding rows [M_c, M_cp) ----------------
__global__ void zeropad_kernel(const int* __restrict__ header, unsigned short* __restrict__ h_c)
{
    const int Mc = header[0], Mcp = header[1];
    const int nel = (Mcp - Mc) * 128;
    for (int e = blockIdx.x * 256 + threadIdx.x; e < nel; e += gridDim.x * 256)
        h_c[Mc * 128 + e] = 0;
}

// ---------------- weight prep: fp32 -> bf16, transposed to [N][K] ----------------
__global__ void convert_kernel(
    const float* __restrict__ lw1, const float* __restrict__ lw2, const float* __restrict__ fw,
    short* __restrict__ lw1t, short* __restrict__ lw2t, short* __restrict__ fwt)
{
    int t = blockIdx.x * 256 + threadIdx.x;
    if (t < 131072) {                       // lw1t[512][256] <- lw1[256][512]
        int n = t >> 8, k = t & 255;
        lw1t[t] = (short)f2bf(lw1[k * 512 + n]);
    } else if (t < 131072 + 524288) {       // lw2t[1024][512] <- lw2[512][1024]
        int u = t - 131072;
        int n = u >> 9, k = u & 511;
        lw2t[u] = (short)f2bf(lw2[k * 1024 + n]);
    } else if (t < 131072 + 524288 + 524288) { // fwt[512][1024] <- fw[1024][511], row 511 = 0
        int v = t - 655360;
        int n = v >> 10, k = v & 1023;
        fwt[v] = (n < 511) ? (short)f2bf(fw[k * 511 + n]) : (short)0;
    }
}

// ---------------- corner MLP -> compacted h_c bf16 [M_c][128] ----------------
#define CB 4
__global__ __launch_bounds__(256, 2) void corner_kernel(
    const float* __restrict__ fpoc,
    const float* __restrict__ cw1, const float* __restrict__ cb1,
    const float* __restrict__ cw2, const float* __restrict__ cb2,
    const int* __restrict__ scanv,
    unsigned short* __restrict__ h_c)
{
    __shared__ float s_h1[CB * 25 * 64];
    __shared__ float s_cw2[64 * 128];
    __shared__ float s_x[CB * 25 * 2];
    __shared__ int s_off[CB], s_nn[CB];
    const int b0 = blockIdx.x * CB;
    const int t = threadIdx.x;

    for (int e = t; e < 64 * 128; e += 256) s_cw2[e] = cw2[e];
    for (int e = t; e < CB * 50; e += 256) s_x[e] = fpoc[b0 * 50 + e];
    if (t < CB) { int o = scanv[b0 + t]; s_off[t] = o; s_nn[t] = scanv[b0 + t + 1] - o; }
    __syncthreads();

    for (int e = t; e < CB * 25 * 64; e += 256) {
        int i = e >> 6, j = e & 63;
        float v = s_x[i * 2] * cw1[j] + s_x[i * 2 + 1] * cw1[64 + j] + cb1[j];
        s_h1[e] = fmaxf(v, 0.f);
    }
    __syncthreads();

    for (int e = t; e < CB * 25 * 128; e += 256) {
        int i = e >> 7, j = e & 127;
        int g = i / 25, ii = i % 25;
        if (ii < s_nn[g]) {
            float a = cb2[j];
            const float* h1r = &s_h1[i * 64];
            #pragma unroll
            for (int k = 0; k < 64; ++k) a += h1r[k] * s_cw2[k * 128 + j];
            h_c[(size_t)(s_off[g] + ii) * 128 + j] = f2bf(a);
        }
    }
}

// ---------------- gemm1: pair(gathered from h_c) @ lw1t^T -> relu+lb1 -> hid ----------
__global__ __launch_bounds__(256, 2) void gemm1_kernel(
    const unsigned short* __restrict__ h_c,   // [M_cp][128]
    const short* __restrict__ lw1t,           // [512][256]
    const float* __restrict__ lb1,
    const int* __restrict__ rm_next,
    const int* __restrict__ header,
    unsigned short* __restrict__ hid,         // [crows][512] chunk-local
    int row0, int pm)
{
    __shared__ __align__(16) char ldsA[16384];
    __shared__ __align__(16) char ldsB[16384];
    __shared__ int s_next[128];

    const int Mcp = header[1];
    int rem = Mcp - row0;
    int apm = (rem <= 0) ? 0 : min(pm, (rem + 127) >> 7);
    int pr, pc;
    if (!tile_assign(blockIdx.x, apm, 2, pr, pc)) return;
    const int Rl = pr * 128;                          // chunk-local
    const int R = row0 + Rl;                          // global compact row base

    const int t = threadIdx.x;
    const int w = t >> 6, l = t & 63, q = l >> 4, ln = l & 15;
    const int wr = w >> 1, wc = w & 1;

    if (t < 128) s_next[t] = rm_next[R + t];
    __syncthreads();

    f32x4 acc[4][4];
    #pragma unroll
    for (int m = 0; m < 4; ++m)
        #pragma unroll
        for (int n = 0; n < 4; ++n) acc[m][n] = 0;

    #pragma unroll
    for (int kt = 0; kt < 4; ++kt) {
        const int k0 = kt * 64;
        // ---- stage A: gather pair rows (pre-swizzled source)
        #pragma unroll
        for (int i = 0; i < 4; ++i) {
            int o = i * 4096 + t * 16;
            int row = o >> 7, colb = o & 127;
            int colb2 = colb ^ ((row & 7) << 4);
            int k = k0 + (colb2 >> 1);                // 0..255 (compile-time half per kt)
            int srow, kk2;
            if (k < 128) { srow = R + row; kk2 = k; }
            else { srow = s_next[row]; kk2 = k - 128; }
            const unsigned short* src = h_c + (size_t)srow * 128 + kk2;
            gload16(src, ldsA + o);
        }
        // ---- stage B from lw1t
        #pragma unroll
        for (int i = 0; i < 4; ++i) {
            int o = i * 4096 + t * 16;
            int row = o >> 7, colb = o & 127;
            int colb2 = colb ^ ((row & 7) << 4);
            const short* src = lw1t + (pc * 128 + row) * 256 + k0 + (colb2 >> 1);
            gload16(src, ldsB + o);
        }
        asm volatile("s_waitcnt vmcnt(0)");
        __syncthreads();
        #pragma unroll
        for (int kk = 0; kk < 2; ++kk) {
            bf16x8 af[4], bf[4];
            #pragma unroll
            for (int m = 0; m < 4; ++m) {
                int row = wr * 64 + m * 16 + ln;
                int off = (row * 128 + kk * 64 + q * 16) ^ ((row & 7) << 4);
                af[m] = *(const bf16x8*)(ldsA + off);
            }
            #pragma unroll
            for (int n = 0; n < 4; ++n) {
                int row = wc * 64 + n * 16 + ln;
                int off = (row * 128 + kk * 64 + q * 16) ^ ((row & 7) << 4);
                bf[n] = *(const bf16x8*)(ldsB + off);
            }
            #pragma unroll
            for (int m = 0; m < 4; ++m)
                #pragma unroll
                for (int n = 0; n < 4; ++n)
                    acc[m][n] = MFMA16(af[m], bf[n], acc[m][n]);
        }
        __syncthreads();
    }
    // ---- epilogue: relu + bias -> hid bf16 (chunk-local rows)
    #pragma unroll
    for (int n = 0; n < 4; ++n) {
        int col = pc * 128 + wc * 64 + n * 16 + ln;
        float bias = lb1[col];
        #pragma unroll
        for (int m = 0; m < 4; ++m) {
            int lrow = Rl + wr * 64 + m * 16 + q * 4;
            #pragma unroll
            for (int r = 0; r < 4; ++r)
                hid[(size_t)(lrow + r) * 512 + col] = f2bf(fmaxf(acc[m][n][r] + bias, 0.f));
        }
    }
}

// ---------------- gemm2: hid @ lw2t^T + segmented maxpool -> scratch partials ----------
__global__ __launch_bounds__(256, 2) void gemm2_kernel(
    const unsigned short* __restrict__ hid,   // [crows][512] chunk-local
    const short* __restrict__ lw2t,           // [1024][512]
    const int* __restrict__ rm_b,
    const int* __restrict__ scanv,
    const int* __restrict__ header,
    float* __restrict__ scratch,              // [4096][2][1024] f32
    int row0, int pm)
{
    __shared__ __align__(16) char smem[33280];   // K-loop: A(16K)+B(16K); epilogue: f32[64][130]
    __shared__ int s_batch[128];

    const int Mcp = header[1];
    int rem = Mcp - row0;
    int apm = (rem <= 0) ? 0 : min(pm, (rem + 127) >> 7);
    int pr, pc;
    if (!tile_assign(blockIdx.x, apm, 3, pr, pc)) return;
    const int Rl = pr * 128;
    const int R = row0 + Rl;

    const int t = threadIdx.x;
    const int w = t >> 6, l = t & 63, q = l >> 4, ln = l & 15;
    const int wr = w >> 1, wc = w & 1;
    char* ldsA = smem;
    char* ldsB = smem + 16384;

    if (t < 128) s_batch[t] = rm_b[R + t];
    __syncthreads();

    f32x4 acc[4][4];
    #pragma unroll
    for (int m = 0; m < 4; ++m)
        #pragma unroll
        for (int n = 0; n < 4; ++n) acc[m][n] = 0;

    for (int kt = 0; kt < 8; ++kt) {
        const int k0 = kt * 64;
        #pragma unroll
        for (int i = 0; i < 4; ++i) {
            int o = i * 4096 + t * 16;
            int row = o >> 7, colb = o & 127;
            int colb2 = colb ^ ((row & 7) << 4);
            const unsigned short* src = hid + (size_t)(Rl + row) * 512 + k0 + (colb2 >> 1);
            gload16(src, ldsA + o);
        }
        #pragma unroll
        for (int i = 0; i < 4; ++i) {
            int o = i * 4096 + t * 16;
            int row = o >> 7, colb = o & 127;
            int colb2 = colb ^ ((row & 7) << 4);
            const short* src = lw2t + (pc * 128 + row) * 512 + k0 + (colb2 >> 1);
            gload16(src, ldsB + o);
        }
        asm volatile("s_waitcnt vmcnt(0)");
        __syncthreads();
        #pragma unroll
        for (int kk = 0; kk < 2; ++kk) {
            bf16x8 af[4], bf[4];
            #pragma unroll
            for (int m = 0; m < 4; ++m) {
                int row = wr * 64 + m * 16 + ln;
                int off = (row * 128 + kk * 64 + q * 16) ^ ((row & 7) << 4);
                af[m] = *(const bf16x8*)(ldsA + off);
            }
            #pragma unroll
            for (int n = 0; n < 4; ++n) {
                int row = wc * 64 + n * 16 + ln;
                int off = (row * 128 + kk * 64 + q * 16) ^ ((row & 7) << 4);
                bf[n] = *(const bf16x8*)(ldsB + off);
            }
            #pragma unroll
            for (int m = 0; m < 4; ++m)
                #pragma unroll
                for (int n = 0; n < 4; ++n)
                    acc[m][n] = MFMA16(af[m], bf[n], acc[m][n]);
        }
        __syncthreads();
    }

    // ---- segmented maxpool epilogue: stage 64-row halves to LDS, walk columns
    float* s_f32 = (float*)smem;    // [64][130] f32 (stride 130 -> 2-way conflicts only)
    float curmax = 0.f;
    int curb = -1;
    #pragma unroll 1
    for (int h = 0; h < 2; ++h) {
        if (wr == h) {
            #pragma unroll
            for (int m = 0; m < 4; ++m)
                #pragma unroll
                for (int n = 0; n < 4; ++n)
                    #pragma unroll
                    for (int r = 0; r < 4; ++r)
                        s_f32[(m * 16 + q * 4 + r) * 130 + wc * 64 + n * 16 + ln] = acc[m][n][r];
        }
        __syncthreads();
        if (t < 128) {
            #pragma unroll 8
            for (int row = 0; row < 64; ++row) {
                int b = s_batch[h * 64 + row];
                float v = s_f32[row * 130 + t];
                if (b == curb) {
                    curmax = fmaxf(curmax, v);
                } else {
                    if (curb >= 0) {
                        int slot = (scanv[curb] < R) ? 1 : 0;
                        scratch[((size_t)curb * 2 + slot) * 1024 + pc * 128 + t] = curmax;
                    }
                    curb = b;
                    curmax = v;
                }
            }
        }
        __syncthreads();
    }
    if (t < 128 && curb >= 0) {
        int slot = (scanv[curb] < R) ? 1 : 0;
        scratch[((size_t)curb * 2 + slot) * 1024 + pc * 128 + t] = curmax;
    }
}

// ---------------- merge: max of <=2 partials + lb2 -> pooled bf16 ----------------
__global__ void merge_kernel(const float* __restrict__ scratch, const int* __restrict__ scanv,
                             const float* __restrict__ lb2, unsigned short* __restrict__ pooled_b)
{
    const int bid = blockIdx.x;          // 16384 blocks
    const int b = bid >> 2;
    const int col = (bid & 3) * 256 + threadIdx.x;
    const int o0 = scanv[b], o1 = scanv[b + 1];
    const bool spans = (o0 >> 7) != ((o1 - 1) >> 7);
    float v = scratch[((size_t)b * 2) * 1024 + col];
    if (spans) v = fmaxf(v, scratch[((size_t)b * 2 + 1) * 1024 + col]);
    pooled_b[(size_t)b * 1024 + col] = f2bf(v + lb2[col]);
}

// ---------------- final: pooled[4096,1024] @ fw[1024,511] + fb ----------------
__global__ __launch_bounds__(512, 2) void final_kernel(
    const unsigned short* __restrict__ pooled_b,
    const short* __restrict__ fwt,    // bf16 [512][1024]
    const float* __restrict__ fb,
    float* __restrict__ out)
{
    const int tid = threadIdx.x;
    const int w = tid >> 6, l = tid & 63, q = l >> 4, ln = l & 15;
    const int rb = blockIdx.x * 128 + w * 16;
    const int nb0 = blockIdx.y * 64;

    f32x4 acc[4];
    #pragma unroll
    for (int j = 0; j < 4; ++j) acc[j] = 0;

    const short* pb = (const short*)pooled_b;
    #pragma unroll 4
    for (int ks = 0; ks < 32; ++ks) {
        bf16x8 a = *(const bf16x8*)(pb + (rb + ln) * 1024 + ks * 32 + q * 8);
        #pragma unroll
        for (int j = 0; j < 4; ++j) {
            bf16x8 bf = *(const bf16x8*)(fwt + (nb0 + j * 16 + ln) * 1024 + ks * 32 + q * 8);
            acc[j] = MFMA16(a, bf, acc[j]);
        }
    }
    #pragma unroll
    for (int j = 0; j < 4; ++j) {
        int col = nb0 + j * 16 + ln;
        if (col < 511) {
            float bias = fb[col];
            #pragma unroll
            for (int r = 0; r < 4; ++r) {
                int row = rb + q * 4 + r;
                out[row * 511 + col] = acc[j][r] + bias;
            }
        }
    }
}

extern "C" void kernel_launch(void* const* d_in, const int* in_sizes, int n_in,
                              void* d_out, int out_size, void* d_ws, size_t ws_size,
                              hipStream_t stream)
{
    const float* fpoc = (const float*)d_in[0];
    const float* cw1  = (const float*)d_in[1];
    const float* cb1  = (const float*)d_in[2];
    const float* cw2  = (const float*)d_in[3];
    const float* cb2  = (const float*)d_in[4];
    const float* lw1  = (const float*)d_in[5];
    const float* lb1  = (const float*)d_in[6];
    const float* lw2  = (const float*)d_in[7];
    const float* lb2  = (const float*)d_in[8];
    const float* fw   = (const float*)d_in[9];
    const float* fb   = (const float*)d_in[10];
    const int*  nfpc  = (const int*)d_in[11];

    char* ws = (char*)d_ws;
    unsigned short* pooled_b = (unsigned short*)(ws + WS_POOLED);
    short* lw1t   = (short*)(ws + WS_LW1T);
    short* lw2t   = (short*)(ws + WS_LW2T);
    short* fwt    = (short*)(ws + WS_FWT);
    int*   scanv  = (int*)(ws + WS_SCAN);
    int*   header = (int*)(ws + WS_HEADER);
    int*   rm_b   = (int*)(ws + WS_RMB);
    int*   rm_next= (int*)(ws + WS_RMNEXT);
    unsigned short* h_c = (unsigned short*)(ws + WS_HC);
    float* scratch = (float*)(ws + WS_SCRATCH);
    unsigned short* hid = (unsigned short*)(ws + WS_HID);

    // adaptive chunking of hid (worst case 102400 rows x 512 x bf16 = 100 MB)
    size_t avail = (ws_size > WS_HID) ? ws_size - WS_HID : 0;
    int n_chunks = 1;
    while (n_chunks < 16 && (size_t)(104857600u / n_chunks) > avail) n_chunks <<= 1;
    const int crows = 102400 / n_chunks;
    const int pm = crows / 128;

    hipLaunchKernelGGL(scan_kernel, dim3(1), dim3(256), 0, stream, nfpc, scanv, header);
    hipLaunchKernelGGL(rowmap_kernel, dim3(400), dim3(256), 0, stream, scanv, header, rm_b, rm_next);
    hipLaunchKernelGGL(zeropad_kernel, dim3(64), dim3(256), 0, stream, header, h_c);
    hipLaunchKernelGGL(convert_kernel, dim3(4608), dim3(256), 0, stream,
                       lw1, lw2, fw, lw1t, lw2t, fwt);
    hipLaunchKernelGGL(corner_kernel, dim3(1024), dim3(256), 0, stream,
                       fpoc, cw1, cb1, cw2, cb2, scanv, h_c);
    const int g1 = ((pm * 4 + 7) / 8) * 8;   // grid covers worst-case per-XCD share
    const int g2 = pm * 8;
    for (int c = 0; c < n_chunks; ++c) {
        int row0 = c * crows;
        hipLaunchKernelGGL(gemm1_kernel, dim3(g1), dim3(256), 0, stream,
                           h_c, lw1t, lb1, rm_next, header, hid, row0, pm);
        hipLaunchKernelGGL(gemm2_kernel, dim3(g2), dim3(256), 0, stream,
                           hid, lw2t, rm_b, scanv, header, scratch, row0, pm);
    }
    hipLaunchKernelGGL(merge_kernel, dim3(16384), dim3(256), 0, stream,
                       scratch, scanv, lb2, pooled_b);
    hipLaunchKernelGGL(final_kernel, dim3(32, 8), dim3(512), 0, stream,
                       pooled_b, fwt, fb, (float*)d_out);
}

// Round 7
// 211.430 us; speedup vs baseline: 1.6787x; 1.2757x over previous
//
#include <hip/hip_runtime.h>

typedef __attribute__((ext_vector_type(8))) short bf16x8;
typedef __attribute__((ext_vector_type(4))) float f32x4;

#define MFMA16(a, b, c) __builtin_amdgcn_mfma_f32_16x16x32_bf16((a), (b), (c), 0, 0, 0)

static __device__ __forceinline__ unsigned short f2bf(float x) {
    union { float f; unsigned u; } v; v.f = x;
    unsigned r = v.u + 0x7fffu + ((v.u >> 16) & 1u);
    return (unsigned short)(r >> 16);
}

// async global->LDS, 16B per lane. LDS dest = wave base + lane*16 (linear).
static __device__ __forceinline__ void gload16(const void* g, void* l) {
    __builtin_amdgcn_global_load_lds(
        (const __attribute__((address_space(1))) unsigned int*)g,
        (__attribute__((address_space(3))) unsigned int*)l, 16, 0, 0);
}

// Balanced data-dependent tile assignment: XCD k = bid&7 gets active-tile range
// [T*k/8, T*(k+1)/8) (bijective chunked, m204). pc-fast => contiguous pr per XCD.
static __device__ __forceinline__ bool tile_assign(int bid, int apm, int npc_log2,
                                                   int& pr, int& pc) {
    const int k = bid & 7, j = bid >> 3;
    const int T = apm << npc_log2;
    const int lo = (T * k) >> 3, hi = (T * (k + 1)) >> 3;
    const int tix = lo + j;
    if (tix >= hi) return false;
    pc = tix & ((1 << npc_log2) - 1);
    pr = tix >> npc_log2;
    return true;
}

// ---------------- workspace layout (bytes) ----------------
#define WS_POOLED   0u          //  8,388,608  bf16 [4096][1024]
#define WS_LW1T     8388608u    //    262,144  bf16 [512][256]
#define WS_LW2T     8650752u    //  1,048,576  bf16 [1024][512]
#define WS_FWT      9699328u    //  1,048,576  bf16 [512][1024]
#define WS_SCAN     10747904u   //     16,640  int [4097]
#define WS_HEADER   10764544u   //        256  int: {M_c, M_cp}
#define WS_RMB      10764800u   //    409,600  int [102400]
#define WS_RMNEXT   11174400u   //    409,600  int [102400]
#define WS_HC       11584000u   // 26,214,400  bf16 [102400][128]
#define WS_SCRATCH  37798400u   // 33,554,432  f32 [4096][2][1024]
#define WS_HID      71352832u   // up to 104,857,600  bf16 [102400][512]

// ---------------- convert (fp32->bf16 transposed weights) + scan (block 4608) ------
__global__ void convert_scan_kernel(
    const float* __restrict__ lw1, const float* __restrict__ lw2, const float* __restrict__ fw,
    short* __restrict__ lw1t, short* __restrict__ lw2t, short* __restrict__ fwt,
    const int* __restrict__ nfpc, int* __restrict__ scanv, int* __restrict__ header)
{
    if (blockIdx.x == 4608) {
        // exclusive prefix sum of nfpc[4096]
        __shared__ int s[256];
        const int t = threadIdx.x;
        int loc[16]; int sum = 0;
        #pragma unroll
        for (int i = 0; i < 16; ++i) { loc[i] = sum; sum += nfpc[t * 16 + i]; }
        s[t] = sum;
        __syncthreads();
        for (int d = 1; d < 256; d <<= 1) {
            int v = (t >= d) ? s[t - d] : 0;
            __syncthreads();
            s[t] += v;
            __syncthreads();
        }
        int excl = (t == 0) ? 0 : s[t - 1];
        #pragma unroll
        for (int i = 0; i < 16; ++i) scanv[t * 16 + i] = excl + loc[i];
        if (t == 255) {
            int M = s[255];
            scanv[4096] = M;
            header[0] = M;
            header[1] = (M + 127) & ~127;
        }
        return;
    }
    int t = blockIdx.x * 256 + threadIdx.x;
    if (t < 131072) {                       // lw1t[512][256] <- lw1[256][512]
        int n = t >> 8, k = t & 255;
        lw1t[t] = (short)f2bf(lw1[k * 512 + n]);
    } else if (t < 131072 + 524288) {       // lw2t[1024][512] <- lw2[512][1024]
        int u = t - 131072;
        int n = u >> 9, k = u & 511;
        lw2t[u] = (short)f2bf(lw2[k * 1024 + n]);
    } else if (t < 131072 + 524288 + 524288) { // fwt[512][1024] <- fw[1024][511], row 511 = 0
        int v = t - 655360;
        int n = v >> 10, k = v & 1023;
        fwt[v] = (n < 511) ? (short)f2bf(fw[k * 511 + n]) : (short)0;
    }
}

// ---------------- rowmap + zero h_c padding rows ----------------
__global__ void rowmap_kernel(const int* __restrict__ scanv, const int* __restrict__ header,
                              int* __restrict__ rm_b, int* __restrict__ rm_next,
                              unsigned short* __restrict__ h_c)
{
    int r = blockIdx.x * 256 + threadIdx.x;     // grid covers 102400
    if (r >= 102400) return;
    const int Mc = header[0];
    if (r >= Mc) {
        rm_b[r] = -1; rm_next[r] = r;
        if (r < header[1]) {
            ushort4 z = {0, 0, 0, 0};
            #pragma unroll
            for (int j = 0; j < 128; j += 4)
                *(ushort4*)&h_c[(size_t)r * 128 + j] = z;
        }
        return;
    }
    int lo = 0, hi = 4096;
    while (hi - lo > 1) { int mid = (lo + hi) >> 1; if (scanv[mid] <= r) lo = mid; else hi = mid; }
    int b = lo, ii = r - scanv[b], n = scanv[b + 1] - scanv[b];
    rm_b[r] = b;
    rm_next[r] = (ii + 1 == n) ? scanv[b] : r + 1;
}

// ---------------- corner MLP -> compacted h_c bf16 [M_c][128] ----------------
#define CB 4
__global__ __launch_bounds__(256, 2) void corner_kernel(
    const float* __restrict__ fpoc,
    const float* __restrict__ cw1, const float* __restrict__ cb1,
    const float* __restrict__ cw2, const float* __restrict__ cb2,
    const int* __restrict__ scanv,
    unsigned short* __restrict__ h_c)
{
    __shared__ float s_h1[CB * 25 * 64];
    __shared__ float s_cw2[64 * 128];
    __shared__ float s_x[CB * 25 * 2];
    __shared__ int s_off[CB], s_nn[CB];
    const int b0 = blockIdx.x * CB;
    const int t = threadIdx.x;

    for (int e = t; e < 64 * 128; e += 256) s_cw2[e] = cw2[e];
    for (int e = t; e < CB * 50; e += 256) s_x[e] = fpoc[b0 * 50 + e];
    if (t < CB) { int o = scanv[b0 + t]; s_off[t] = o; s_nn[t] = scanv[b0 + t + 1] - o; }
    __syncthreads();

    for (int e = t; e < CB * 25 * 64; e += 256) {
        int i = e >> 6, j = e & 63;
        float v = s_x[i * 2] * cw1[j] + s_x[i * 2 + 1] * cw1[64 + j] + cb1[j];
        s_h1[e] = fmaxf(v, 0.f);
    }
    __syncthreads();

    // layer 2: float4 per thread (ds_read_b128 on cw2)
    for (int e = t; e < CB * 25 * 32; e += 256) {
        int i = e >> 5, j4 = (e & 31) * 4;
        int g = i / 25, ii = i % 25;
        if (ii < s_nn[g]) {
            float4 a = *(const float4*)(cb2 + j4);
            const float* h1r = &s_h1[i * 64];
            #pragma unroll
            for (int k = 0; k < 64; ++k) {
                float hv = h1r[k];
                float4 wv = *(const float4*)(s_cw2 + k * 128 + j4);
                a.x += hv * wv.x; a.y += hv * wv.y; a.z += hv * wv.z; a.w += hv * wv.w;
            }
            ushort4 o;
            o.x = f2bf(a.x); o.y = f2bf(a.y); o.z = f2bf(a.z); o.w = f2bf(a.w);
            *(ushort4*)&h_c[(size_t)(s_off[g] + ii) * 128 + j4] = o;
        }
    }
}

// ---------------- gemm1: pair(gathered from h_c) @ lw1t^T -> relu+lb1 -> hid ----------
__global__ __launch_bounds__(256, 4) void gemm1_kernel(
    const unsigned short* __restrict__ h_c,   // [M_cp][128]
    const short* __restrict__ lw1t,           // [512][256]
    const float* __restrict__ lb1,
    const int* __restrict__ rm_next,
    const int* __restrict__ header,
    unsigned short* __restrict__ hid,         // [crows][512] chunk-local
    int row0, int pm)
{
    __shared__ __align__(16) char ldsA[16384];
    __shared__ __align__(16) char ldsB[16384];
    __shared__ int s_next[128];

    const int Mcp = header[1];
    int rem = Mcp - row0;
    int apm = (rem <= 0) ? 0 : min(pm, (rem + 127) >> 7);
    int pr, pc;
    if (!tile_assign(blockIdx.x, apm, 2, pr, pc)) return;
    const int Rl = pr * 128;                          // chunk-local
    const int R = row0 + Rl;                          // global compact row base

    const int t = threadIdx.x;
    const int w = t >> 6, l = t & 63, q = l >> 4, ln = l & 15;
    const int wr = w >> 1, wc = w & 1;

    if (t < 128) s_next[t] = rm_next[R + t];
    __syncthreads();

    f32x4 acc[4][4];
    #pragma unroll
    for (int m = 0; m < 4; ++m)
        #pragma unroll
        for (int n = 0; n < 4; ++n) acc[m][n] = 0;

    #pragma unroll
    for (int kt = 0; kt < 4; ++kt) {
        const int k0 = kt * 64;
        // ---- stage A: gather pair rows (pre-swizzled source)
        #pragma unroll
        for (int i = 0; i < 4; ++i) {
            int o = i * 4096 + t * 16;
            int row = o >> 7, colb = o & 127;
            int colb2 = colb ^ ((row & 7) << 4);
            int k = k0 + (colb2 >> 1);                // 0..255 (compile-time half per kt)
            int srow, kk2;
            if (k < 128) { srow = R + row; kk2 = k; }
            else { srow = s_next[row]; kk2 = k - 128; }
            const unsigned short* src = h_c + (size_t)srow * 128 + kk2;
            gload16(src, ldsA + o);
        }
        // ---- stage B from lw1t
        #pragma unroll
        for (int i = 0; i < 4; ++i) {
            int o = i * 4096 + t * 16;
            int row = o >> 7, colb = o & 127;
            int colb2 = colb ^ ((row & 7) << 4);
            const short* src = lw1t + (pc * 128 + row) * 256 + k0 + (colb2 >> 1);
            gload16(src, ldsB + o);
        }
        asm volatile("s_waitcnt vmcnt(0)");
        __syncthreads();
        #pragma unroll
        for (int kk = 0; kk < 2; ++kk) {
            bf16x8 af[4], bf[4];
            #pragma unroll
            for (int m = 0; m < 4; ++m) {
                int row = wr * 64 + m * 16 + ln;
                int off = (row * 128 + kk * 64 + q * 16) ^ ((row & 7) << 4);
                af[m] = *(const bf16x8*)(ldsA + off);
            }
            #pragma unroll
            for (int n = 0; n < 4; ++n) {
                int row = wc * 64 + n * 16 + ln;
                int off = (row * 128 + kk * 64 + q * 16) ^ ((row & 7) << 4);
                bf[n] = *(const bf16x8*)(ldsB + off);
            }
            #pragma unroll
            for (int m = 0; m < 4; ++m)
                #pragma unroll
                for (int n = 0; n < 4; ++n)
                    acc[m][n] = MFMA16(af[m], bf[n], acc[m][n]);
        }
        __syncthreads();
    }
    // ---- epilogue: relu + bias -> hid bf16 (chunk-local rows)
    #pragma unroll
    for (int n = 0; n < 4; ++n) {
        int col = pc * 128 + wc * 64 + n * 16 + ln;
        float bias = lb1[col];
        #pragma unroll
        for (int m = 0; m < 4; ++m) {
            int lrow = Rl + wr * 64 + m * 16 + q * 4;
            #pragma unroll
            for (int r = 0; r < 4; ++r)
                hid[(size_t)(lrow + r) * 512 + col] = f2bf(fmaxf(acc[m][n][r] + bias, 0.f));
        }
    }
}

// ---------------- gemm2: hid @ lw2t^T + segmented maxpool -> scratch partials ----------
__global__ __launch_bounds__(256, 4) void gemm2_kernel(
    const unsigned short* __restrict__ hid,   // [crows][512] chunk-local
    const short* __restrict__ lw2t,           // [1024][512]
    const int* __restrict__ rm_b,
    const int* __restrict__ scanv,
    const int* __restrict__ header,
    float* __restrict__ scratch,              // [4096][2][1024] f32
    int row0, int pm)
{
    __shared__ __align__(16) char smem[33280];   // K-loop: A(16K)+B(16K); epilogue: f32[64][130]
    __shared__ int s_batch[128];

    const int Mcp = header[1];
    int rem = Mcp - row0;
    int apm = (rem <= 0) ? 0 : min(pm, (rem + 127) >> 7);
    int pr, pc;
    if (!tile_assign(blockIdx.x, apm, 3, pr, pc)) return;
    const int Rl = pr * 128;
    const int R = row0 + Rl;

    const int t = threadIdx.x;
    const int w = t >> 6, l = t & 63, q = l >> 4, ln = l & 15;
    const int wr = w >> 1, wc = w & 1;
    char* ldsA = smem;
    char* ldsB = smem + 16384;

    if (t < 128) s_batch[t] = rm_b[R + t];
    __syncthreads();

    f32x4 acc[4][4];
    #pragma unroll
    for (int m = 0; m < 4; ++m)
        #pragma unroll
        for (int n = 0; n < 4; ++n) acc[m][n] = 0;

    for (int kt = 0; kt < 8; ++kt) {
        const int k0 = kt * 64;
        #pragma unroll
        for (int i = 0; i < 4; ++i) {
            int o = i * 4096 + t * 16;
            int row = o >> 7, colb = o & 127;
            int colb2 = colb ^ ((row & 7) << 4);
            const unsigned short* src = hid + (size_t)(Rl + row) * 512 + k0 + (colb2 >> 1);
            gload16(src, ldsA + o);
        }
        #pragma unroll
        for (int i = 0; i < 4; ++i) {
            int o = i * 4096 + t * 16;
            int row = o >> 7, colb = o & 127;
            int colb2 = colb ^ ((row & 7) << 4);
            const short* src = lw2t + (pc * 128 + row) * 512 + k0 + (colb2 >> 1);
            gload16(src, ldsB + o);
        }
        asm volatile("s_waitcnt vmcnt(0)");
        __syncthreads();
        #pragma unroll
        for (int kk = 0; kk < 2; ++kk) {
            bf16x8 af[4], bf[4];
            #pragma unroll
            for (int m = 0; m < 4; ++m) {
                int row = wr * 64 + m * 16 + ln;
                int off = (row * 128 + kk * 64 + q * 16) ^ ((row & 7) << 4);
                af[m] = *(const bf16x8*)(ldsA + off);
            }
            #pragma unroll
            for (int n = 0; n < 4; ++n) {
                int row = wc * 64 + n * 16 + ln;
                int off = (row * 128 + kk * 64 + q * 16) ^ ((row & 7) << 4);
                bf[n] = *(const bf16x8*)(ldsB + off);
            }
            #pragma unroll
            for (int m = 0; m < 4; ++m)
                #pragma unroll
                for (int n = 0; n < 4; ++n)
                    acc[m][n] = MFMA16(af[m], bf[n], acc[m][n]);
        }
        __syncthreads();
    }

    // ---- segmented maxpool epilogue: stage 64-row halves, walk 32-row units.
    // A batch (n<=25<32) spans at most 2 consecutive 32-row units ->
    // slot = (batch started before this unit) ? 1 : 0.
    // NOTE: s_f32 holds only the current 64-row HALF; its row index is
    // half-local (esub*32 + row), NOT tile-local (rb + row).  [R6 bug fix]
    float* s_f32 = (float*)smem;    // [64][130] f32 (stride 130: conflict-free)
    const int ecol = t & 127, esub = t >> 7;     // 256 threads: 128 cols x 2 units
    #pragma unroll 1
    for (int h = 0; h < 2; ++h) {
        if (wr == h) {
            #pragma unroll
            for (int m = 0; m < 4; ++m)
                #pragma unroll
                for (int n = 0; n < 4; ++n)
                    #pragma unroll
                    for (int r = 0; r < 4; ++r)
                        s_f32[(m * 16 + q * 4 + r) * 130 + wc * 64 + n * 16 + ln] = acc[m][n][r];
        }
        __syncthreads();
        {
            const int ub = R + h * 64 + esub * 32;   // unit base (global row)
            const int rb = h * 64 + esub * 32;       // tile-local base (s_batch index)
            const int lb = esub * 32;                // half-local base (s_f32 index)
            int curb = s_batch[rb];
            float curmax = s_f32[lb * 130 + ecol];
            #pragma unroll 8
            for (int row = 1; row < 32; ++row) {
                int b = s_batch[rb + row];
                float v = s_f32[(lb + row) * 130 + ecol];
                if (b == curb) {
                    curmax = fmaxf(curmax, v);
                } else {
                    if (curb >= 0) {
                        int slot = (scanv[curb] < ub) ? 1 : 0;
                        scratch[((size_t)curb * 2 + slot) * 1024 + pc * 128 + ecol] = curmax;
                    }
                    curb = b;
                    curmax = v;
                }
            }
            if (curb >= 0) {
                int slot = (scanv[curb] < ub) ? 1 : 0;
                scratch[((size_t)curb * 2 + slot) * 1024 + pc * 128 + ecol] = curmax;
            }
        }
        __syncthreads();
    }
}

// ---------------- merge: max of <=2 partials + lb2 -> pooled bf16 ----------------
__global__ void merge_kernel(const float* __restrict__ scratch, const int* __restrict__ scanv,
                             const float* __restrict__ lb2, unsigned short* __restrict__ pooled_b)
{
    const int b = blockIdx.x;                 // 4096 blocks; thread t does cols 4t..4t+3
    const int col4 = threadIdx.x * 4;
    const int o0 = scanv[b], o1 = scanv[b + 1];
    const bool spans = (o0 >> 5) != ((o1 - 1) >> 5);    // 32-row units
    float4 v = *(const float4*)&scratch[((size_t)b * 2) * 1024 + col4];
    if (spans) {
        float4 u = *(const float4*)&scratch[((size_t)b * 2 + 1) * 1024 + col4];
        v.x = fmaxf(v.x, u.x); v.y = fmaxf(v.y, u.y);
        v.z = fmaxf(v.z, u.z); v.w = fmaxf(v.w, u.w);
    }
    float4 bb = *(const float4*)(lb2 + col4);
    ushort4 o;
    o.x = f2bf(v.x + bb.x); o.y = f2bf(v.y + bb.y);
    o.z = f2bf(v.z + bb.z); o.w = f2bf(v.w + bb.w);
    *(ushort4*)&pooled_b[(size_t)b * 1024 + col4] = o;
}

// ---------------- final: pooled[4096,1024] @ fw[1024,511] + fb ----------------
__global__ __launch_bounds__(512, 2) void final_kernel(
    const unsigned short* __restrict__ pooled_b,
    const short* __restrict__ fwt,    // bf16 [512][1024]
    const float* __restrict__ fb,
    float* __restrict__ out)
{
    const int tid = threadIdx.x;
    const int w = tid >> 6, l = tid & 63, q = l >> 4, ln = l & 15;
    const int rb = blockIdx.x * 128 + w * 16;
    const int nb0 = blockIdx.y * 64;

    f32x4 acc[4];
    #pragma unroll
    for (int j = 0; j < 4; ++j) acc[j] = 0;

    const short* pb = (const short*)pooled_b;
    #pragma unroll 4
    for (int ks = 0; ks < 32; ++ks) {
        bf16x8 a = *(const bf16x8*)(pb + (rb + ln) * 1024 + ks * 32 + q * 8);
        #pragma unroll
        for (int j = 0; j < 4; ++j) {
            bf16x8 bf = *(const bf16x8*)(fwt + (nb0 + j * 16 + ln) * 1024 + ks * 32 + q * 8);
            acc[j] = MFMA16(a, bf, acc[j]);
        }
    }
    #pragma unroll
    for (int j = 0; j < 4; ++j) {
        int col = nb0 + j * 16 + ln;
        if (col < 511) {
            float bias = fb[col];
            #pragma unroll
            for (int r = 0; r < 4; ++r) {
                int row = rb + q * 4 + r;
                out[row * 511 + col] = acc[j][r] + bias;
            }
        }
    }
}

extern "C" void kernel_launch(void* const* d_in, const int* in_sizes, int n_in,
                              void* d_out, int out_size, void* d_ws, size_t ws_size,
                              hipStream_t stream)
{
    const float* fpoc = (const float*)d_in[0];
    const float* cw1  = (const float*)d_in[1];
    const float* cb1  = (const float*)d_in[2];
    const float* cw2  = (const float*)d_in[3];
    const float* cb2  = (const float*)d_in[4];
    const float* lw1  = (const float*)d_in[5];
    const float* lb1  = (const float*)d_in[6];
    const float* lw2  = (const float*)d_in[7];
    const float* lb2  = (const float*)d_in[8];
    const float* fw   = (const float*)d_in[9];
    const float* fb   = (const float*)d_in[10];
    const int*  nfpc  = (const int*)d_in[11];

    char* ws = (char*)d_ws;
    unsigned short* pooled_b = (unsigned short*)(ws + WS_POOLED);
    short* lw1t   = (short*)(ws + WS_LW1T);
    short* lw2t   = (short*)(ws + WS_LW2T);
    short* fwt    = (short*)(ws + WS_FWT);
    int*   scanv  = (int*)(ws + WS_SCAN);
    int*   header = (int*)(ws + WS_HEADER);
    int*   rm_b   = (int*)(ws + WS_RMB);
    int*   rm_next= (int*)(ws + WS_RMNEXT);
    unsigned short* h_c = (unsigned short*)(ws + WS_HC);
    float* scratch = (float*)(ws + WS_SCRATCH);
    unsigned short* hid = (unsigned short*)(ws + WS_HID);

    // adaptive chunking of hid (worst case 102400 rows x 512 x bf16 = 100 MB)
    size_t avail = (ws_size > WS_HID) ? ws_size - WS_HID : 0;
    int n_chunks = 1;
    while (n_chunks < 16 && (size_t)(104857600u / n_chunks) > avail) n_chunks <<= 1;
    const int crows = 102400 / n_chunks;
    const int pm = crows / 128;

    hipLaunchKernelGGL(convert_scan_kernel, dim3(4609), dim3(256), 0, stream,
                       lw1, lw2, fw, lw1t, lw2t, fwt, nfpc, scanv, header);
    hipLaunchKernelGGL(rowmap_kernel, dim3(400), dim3(256), 0, stream,
                       scanv, header, rm_b, rm_next, h_c);
    hipLaunchKernelGGL(corner_kernel, dim3(1024), dim3(256), 0, stream,
                       fpoc, cw1, cb1, cw2, cb2, scanv, h_c);
    const int g1 = ((pm * 4 + 7) / 8) * 8;   // grid covers worst-case per-XCD share
    const int g2 = pm * 8;
    for (int c = 0; c < n_chunks; ++c) {
        int row0 = c * crows;
        hipLaunchKernelGGL(gemm1_kernel, dim3(g1), dim3(256), 0, stream,
                           h_c, lw1t, lb1, rm_next, header, hid, row0, pm);
        hipLaunchKernelGGL(gemm2_kernel, dim3(g2), dim3(256), 0, stream,
                           hid, lw2t, rm_b, scanv, header, scratch, row0, pm);
    }
    hipLaunchKernelGGL(merge_kernel, dim3(4096), dim3(256), 0, stream,
                       scratch, scanv, lb2, pooled_b);
    hipLaunchKernelGGL(final_kernel, dim3(32, 8), dim3(512), 0, stream,
                       pooled_b, fwt, fb, (float*)d_out);
}